// Round 6
// baseline (35593.552 us; speedup 1.0000x reference)
//
#include <hip/hip_runtime.h>
#include <math.h>

#define B_DIM 256
#define T_DIM 365
#define I_DIM 32
#define H_DIM 256
#define S_DIM 27
#define L_DIM 7
#define FL_DIM 56
#define NB 8          // blocks per cluster
#define NCL 32        // clusters
#define RPC 8         // batch rows per cluster
#define THR 384       // threads per main block (6 waves)
#define GC 96         // gate-cols per block (3 gates x 32 hidden cols)
#define CH 36         // K chunks of 8 f16 (K=288)

typedef __attribute__((ext_vector_type(2))) _Float16 half2v;

__device__ __forceinline__ float fast_rcp(float x) { return __builtin_amdgcn_rcpf(x); }
__device__ __forceinline__ float sigm(float x) { return fast_rcp(1.0f + __expf(-x)); }
__device__ __forceinline__ float tanh_fast(float x) { return 1.0f - 2.0f * fast_rcp(1.0f + __expf(2.0f * x)); }

__device__ __forceinline__ float dot2(uint w, uint s, float acc) {
#if __has_builtin(__builtin_amdgcn_fdot2)
    return __builtin_amdgcn_fdot2(__builtin_bit_cast(half2v, w), __builtin_bit_cast(half2v, s), acc, false);
#else
    half2v a = __builtin_bit_cast(half2v, w), b = __builtin_bit_cast(half2v, s);
    return acc + (float)a.x * (float)b.x + (float)a.y * (float)b.y;
#endif
}
__device__ __forceinline__ ushort f16bits(float v) {
    _Float16 h = (_Float16)v;
    return __builtin_bit_cast(ushort, h);
}
__device__ __forceinline__ uint pk2(float a, float b) {
    half2v p; p.x = (_Float16)a; p.y = (_Float16)b;
    return __builtin_bit_cast(uint, p);
}
#define DOT4(w, s, acc) { acc = dot2(w.x, s.x, acc); acc = dot2(w.y, s.y, acc); \
                          acc = dot2(w.z, s.z, acc); acc = dot2(w.w, s.w, acc); }

// Pack per-block weight slabs: WP[(j*GC+col)*CH+ch] = 8 f16 of W[gc][8ch..8ch+7],
// k<32 -> Wdg[gc][k], else Whg[gc][k-32]; gc = gate*256 + j*32 + hcol, col = gate*32+hcol.
__global__ void k_pack_w(const float* __restrict__ Wdg, const float* __restrict__ Whg,
                         uint4* __restrict__ WP) {
    int idx = blockIdx.x * 256 + threadIdx.x;     // over NB*GC*CH = 27648
    if (idx >= NB * GC * CH) return;
    int ch = idx % CH, col = (idx / CH) % GC, j = idx / (CH * GC);
    int gate = col >> 5, hcol = col & 31;
    int gc = gate * 256 + j * 32 + hcol;
    float v[8];
    for (int q = 0; q < 8; ++q) {
        int k = ch * 8 + q;
        v[q] = (k < I_DIM) ? Wdg[gc * I_DIM + k] : Whg[gc * H_DIM + (k - I_DIM)];
    }
    uint4 o; o.x = pk2(v[0], v[1]); o.y = pk2(v[2], v[3]); o.z = pk2(v[4], v[5]); o.w = pk2(v[6], v[7]);
    WP[idx] = o;
}

// WPQ[i*32+hq] = 8 f16 of Wp0[i][8hq..8hq+7]
__global__ void k_pack_wp(const float* __restrict__ Wp0, uint4* __restrict__ WPQ) {
    int idx = blockIdx.x * 256 + threadIdx.x;     // over 1024
    if (idx >= 32 * 32) return;
    int i = idx >> 5, hq = idx & 31;
    const float* p = Wp0 + i * H_DIM + hq * 8;
    uint4 o; o.x = pk2(p[0], p[1]); o.y = pk2(p[2], p[3]); o.z = pk2(p[4], p[5]); o.w = pk2(p[6], p[7]);
    WPQ[idx] = o;
}

__global__ void k_transpose(const float* __restrict__ in, float* __restrict__ out, int M, int N) {
    int idx = blockIdx.x * 256 + threadIdx.x;
    if (idx >= M * N) return;
    int n = idx / M, m = idx % M;
    out[idx] = in[m * N + n];
}

__global__ void k_igate(const float* __restrict__ st, const float* __restrict__ Wsh,
                        const float* __restrict__ bsh, float* __restrict__ ig) {
    __shared__ float s[S_DIM];
    int b = blockIdx.x, h = threadIdx.x;
    if (h < S_DIM) s[h] = st[b * S_DIM + h];
    __syncthreads();
    float a = bsh[h];
    for (int k = 0; k < S_DIM; ++k) a += s[k] * Wsh[h * S_DIM + k];
    ig[b * H_DIM + h] = sigm(a);
}

// Clustered persistent kernel. Block bid: j = bid>>5 (slab index in cluster, 0..7),
// cl = bid&31 (cluster). Cluster cl owns batch rows 8cl..8cl+7; block j owns hidden
// cols j*32..j*32+31 (all 3 gates) of BOTH layers, weights LDS-resident.
__global__ __launch_bounds__(THR, 1) void k_main(
    const float* __restrict__ x,
    const uint4* __restrict__ W0P, const uint4* __restrict__ W1P, const uint4* __restrict__ WPQ,
    const float* __restrict__ bdg0, const float* __restrict__ bdg1, const float* __restrict__ bp0,
    const float* __restrict__ ig0, const float* __restrict__ ig1,
    ushort* __restrict__ hx0, ushort* __restrict__ hx1, float* __restrict__ hfin,
    uint* ctr) {
    __shared__ uint4 w0l[GC * 37];     // padded stride 37 (bank spread)
    __shared__ uint4 w1l[GC * 37];
    __shared__ uint4 wpl[32 * 33];
    __shared__ uint4 act0[CH][RPC];    // [x_t | h0] per row, 8 f16 per chunk
    __shared__ uint4 act1[CH][RPC];    // [inp1 | h1]
    __shared__ float pre[GC][9];       // gate preacts [col96][row], padded

    const int t = threadIdx.x;
    const int bid = blockIdx.x;
    const int cl = bid & 31, j = bid >> 5;
    const int r0 = cl * RPC;

    // ---- load weight slabs into LDS (once)
    for (int idx = t; idx < GC * CH; idx += THR) {
        int col = idx / CH, ch = idx % CH;
        w0l[col * 37 + ch] = W0P[(j * GC + col) * CH + ch];
        w1l[col * 37 + ch] = W1P[(j * GC + col) * CH + ch];
    }
    for (int idx = t; idx < 32 * 32; idx += THR) {
        int i = idx >> 5, hq = idx & 31;
        wpl[i * 33 + hq] = WPQ[idx];
    }
    uint4 z4 = make_uint4(0u, 0u, 0u, 0u);
    for (int idx = t; idx < CH * RPC; idx += THR) {
        ((uint4*)act0)[idx] = z4; ((uint4*)act1)[idx] = z4;
    }
    __syncthreads();
    if (t < 32) {                      // stage x_0 into act0 chunks 0..3
        int cc = t & 3, row = t >> 2;
        const float4* xp = (const float4*)(x + (size_t)(r0 + row) * (T_DIM * I_DIM) + cc * 8);
        float4 u = xp[0], v = xp[1];
        uint4 o; o.x = pk2(u.x, u.y); o.y = pk2(u.z, u.w); o.z = pk2(v.x, v.y); o.w = pk2(v.z, v.w);
        act0[cc][row] = o;
    }

    // gemm role (all 384 threads): col96 = t%96, rp = t/96 (row pair)
    const int col96 = t % GC, rp = t / GC;
    const int gate = col96 >> 5, hcol = col96 & 31;
    const int gcg = gate * 256 + j * 32 + hcol;
    const float bias0 = bdg0[gcg], bias1 = bdg1[gcg];
    // update role (t<256): uc = hidden col, ur = row
    const int uc = t & 31, ur = t >> 5;
    float ig0v = 0.f, ig1v = 0.f, c0 = 0.f, c1 = 0.f;
    if (t < 256) {
        ig0v = ig0[(r0 + ur) * H_DIM + j * 32 + uc];
        ig1v = ig1[(r0 + ur) * H_DIM + j * 32 + uc];
    }
    float bp0v = (t < 128) ? bp0[t & 31] : 0.f;
    uint* ctrA = ctr;            // [NCL]
    uint* ctrB = ctr + NCL;      // [NCL]
    __syncthreads();

    for (int ts = 0; ts < T_DIM; ++ts) {
        const int par = ts & 1;
        // ---- L0 gemm: pre = [x|h0] @ W0 (+bias), 96 cols x 8 rows
        {
            float a0 = bias0, a1 = bias0;
#pragma unroll
            for (int ch = 0; ch < CH; ++ch) {
                uint4 w = w0l[col96 * 37 + ch];
                uint4 sA = act0[ch][2 * rp], sB = act0[ch][2 * rp + 1];
                DOT4(w, sA, a0); DOT4(w, sB, a1);
            }
            pre[col96][2 * rp] = a0; pre[col96][2 * rp + 1] = a1;
        }
        __syncthreads();                                   // B1
        // ---- update0: c,h for (uc,ur); write h0 slice to exchange buffer
        if (t < 256) {
            float f = sigm(pre[uc][ur]);
            float o = sigm(pre[32 + uc][ur]);
            float g = tanh_fast(pre[64 + uc][ur]);
            c0 = f * c0 + ig0v * g;
            float h = o * tanh_fast(c0);
            hx0[((size_t)(par * NCL + cl) * RPC + ur) * H_DIM + j * 32 + uc] = f16bits(h);
        }
        __threadfence();
        __syncthreads();                                   // B2
        if (t == 0) {
            atomicAdd(&ctrA[cl], 1u);
            while (__hip_atomic_load(&ctrA[cl], __ATOMIC_RELAXED, __HIP_MEMORY_SCOPE_AGENT)
                   < (uint)(NB * (ts + 1))) __builtin_amdgcn_s_sleep(1);
        }
        __syncthreads();                                   // B3
        __threadfence();
        // ---- gather full h0_t into act0 chunks 4..35
        if (t < 256) {
            int cc = t & 31, row = t >> 5;
            const ushort* hp = hx0 + ((size_t)(par * NCL + cl) * RPC + row) * H_DIM + cc * 8;
            act0[4 + cc][row] = *(const uint4*)hp;
        }
        __syncthreads();                                   // B4
        // ---- proj: inp1[row][i] = bp0[i] + h0 . Wp0[i]; write f16 into act1 chunks 0..3
        if (t < 128) {
            int i = t & 31, prp = t >> 5;
            float p0 = bp0v, p1 = bp0v;
#pragma unroll
            for (int hq = 0; hq < 32; ++hq) {
                uint4 w = wpl[i * 33 + hq];
                uint4 sA = act0[4 + hq][2 * prp], sB = act0[4 + hq][2 * prp + 1];
                DOT4(w, sA, p0); DOT4(w, sB, p1);
            }
            ushort* d = (ushort*)act1;
            d[((i >> 3) * RPC + 2 * prp) * 8 + (i & 7)] = f16bits(p0);
            d[((i >> 3) * RPC + 2 * prp + 1) * 8 + (i & 7)] = f16bits(p1);
        }
        __syncthreads();                                   // B5
        // ---- L1 gemm: pre = [inp1|h1] @ W1 (+bias)
        {
            float b0 = bias1, b1 = bias1;
#pragma unroll
            for (int ch = 0; ch < CH; ++ch) {
                uint4 w = w1l[col96 * 37 + ch];
                uint4 sA = act1[ch][2 * rp], sB = act1[ch][2 * rp + 1];
                DOT4(w, sA, b0); DOT4(w, sB, b1);
            }
            pre[col96][2 * rp] = b0; pre[col96][2 * rp + 1] = b1;
        }
        __syncthreads();                                   // B6
        // ---- update1
        if (t < 256) {
            float f = sigm(pre[uc][ur]);
            float o = sigm(pre[32 + uc][ur]);
            float g = tanh_fast(pre[64 + uc][ur]);
            c1 = f * c1 + ig1v * g;
            float h = o * tanh_fast(c1);
            hx1[((size_t)(par * NCL + cl) * RPC + ur) * H_DIM + j * 32 + uc] = f16bits(h);
            if (ts == T_DIM - 1) hfin[(size_t)(r0 + ur) * H_DIM + j * 32 + uc] = h;
        }
        __threadfence();
        __syncthreads();                                   // B7
        if (t == 0) {
            atomicAdd(&ctrB[cl], 1u);
            while (__hip_atomic_load(&ctrB[cl], __ATOMIC_RELAXED, __HIP_MEMORY_SCOPE_AGENT)
                   < (uint)(NB * (ts + 1))) __builtin_amdgcn_s_sleep(1);
        }
        __syncthreads();                                   // B8
        __threadfence();
        // ---- gather h1_t into act1 chunks 4..35 ; stage x_{ts+1} into act0 chunks 0..3
        if (t < 256) {
            int cc = t & 31, row = t >> 5;
            const ushort* hp = hx1 + ((size_t)(par * NCL + cl) * RPC + row) * H_DIM + cc * 8;
            act1[4 + cc][row] = *(const uint4*)hp;
        } else if (t < 288 && ts + 1 < T_DIM) {
            int tt = t - 256, cc = tt & 3, row = tt >> 2;
            const float4* xp = (const float4*)(x + (size_t)(r0 + row) * (T_DIM * I_DIM)
                                               + (ts + 1) * I_DIM + cc * 8);
            float4 u = xp[0], v = xp[1];
            uint4 o; o.x = pk2(u.x, u.y); o.y = pk2(u.z, u.w); o.z = pk2(v.x, v.y); o.w = pk2(v.z, v.w);
            act0[cc][row] = o;
        }
        __syncthreads();                                   // B9
    }
}

// Output heads (post-loop, per 2 rows): out = relu(h1@Wh1^T+bh1)@Wh2^T+bh2 + future head
__global__ __launch_bounds__(256) void k_heads(
    const float* __restrict__ hfin, const float* __restrict__ future,
    const float* __restrict__ Wh1T, const float* __restrict__ bh1,
    const float* __restrict__ Wh2, const float* __restrict__ bh2,
    const float* __restrict__ Wf1T, const float* __restrict__ bf1,
    const float* __restrict__ Wf2, const float* __restrict__ bf2,
    float* __restrict__ out) {
    __shared__ float h1s[2][H_DIM], hA[2][H_DIM], hB[2][H_DIM], futs[2][FL_DIM];
    int t = threadIdx.x, r0 = blockIdx.x * 2;
    h1s[0][t] = hfin[(size_t)r0 * H_DIM + t];
    h1s[1][t] = hfin[(size_t)(r0 + 1) * H_DIM + t];
    if (t < 2 * FL_DIM) { int row = t / FL_DIM, k = t % FL_DIM; futs[row][k] = future[(r0 + row) * FL_DIM + k]; }
    __syncthreads();
    float a0 = bh1[t], a1 = bh1[t];
    for (int h = 0; h < H_DIM; ++h) {
        float w = Wh1T[h * H_DIM + t];
        a0 += w * h1s[0][h]; a1 += w * h1s[1][h];
    }
    hA[0][t] = fmaxf(a0, 0.f); hA[1][t] = fmaxf(a1, 0.f);
    float b0 = bf1[t], b1 = bf1[t];
    for (int k = 0; k < FL_DIM; ++k) {
        float w = Wf1T[k * H_DIM + t];
        b0 += w * futs[0][k]; b1 += w * futs[1][k];
    }
    hB[0][t] = fmaxf(b0, 0.f); hB[1][t] = fmaxf(b1, 0.f);
    __syncthreads();
    if (t < 2 * L_DIM) {
        int row = t / L_DIM, l = t % L_DIM;
        float acc = bh2[l] + bf2[l];
        for (int q = 0; q < H_DIM; ++q)
            acc += hA[row][q] * Wh2[l * H_DIM + q] + hB[row][q] * Wf2[l * H_DIM + q];
        out[(r0 + row) * L_DIM + l] = acc;
    }
}

extern "C" void kernel_launch(void* const* d_in, const int* in_sizes, int n_in,
                              void* d_out, int out_size, void* d_ws, size_t ws_size,
                              hipStream_t stream) {
    const float* x    = (const float*)d_in[0];
    const float* stat = (const float*)d_in[1];
    const float* fut  = (const float*)d_in[2];
    const float* Wsh0 = (const float*)d_in[3];
    const float* bsh0 = (const float*)d_in[4];
    const float* Wdg0 = (const float*)d_in[5];
    const float* bdg0 = (const float*)d_in[6];
    const float* Whg0 = (const float*)d_in[7];
    const float* Wsh1 = (const float*)d_in[8];
    const float* bsh1 = (const float*)d_in[9];
    const float* Wdg1 = (const float*)d_in[10];
    const float* bdg1 = (const float*)d_in[11];
    const float* Whg1 = (const float*)d_in[12];
    const float* Wp0  = (const float*)d_in[13];
    const float* bp0  = (const float*)d_in[14];
    const float* Wh1  = (const float*)d_in[15];
    const float* bh1  = (const float*)d_in[16];
    const float* Wh2  = (const float*)d_in[17];
    const float* bh2  = (const float*)d_in[18];
    const float* Wf1  = (const float*)d_in[19];
    const float* bf1  = (const float*)d_in[20];
    const float* Wf2  = (const float*)d_in[21];
    const float* bf2  = (const float*)d_in[22];

    char* ws = (char*)d_ws;
    uint4* W0P  = (uint4*)(ws + 0);            // 442368 B
    uint4* W1P  = (uint4*)(ws + 442368);       // 442368
    uint4* WPQ  = (uint4*)(ws + 884736);       // 16384
    float* Wh1T = (float*)(ws + 901120);       // 262144
    float* Wf1T = (float*)(ws + 1163264);      // 57344
    float* ig0  = (float*)(ws + 1220608);      // 262144
    float* ig1  = (float*)(ws + 1482752);      // 262144
    float* hfin = (float*)(ws + 1744896);      // 262144
    ushort* hx0 = (ushort*)(ws + 2007040);     // 262144
    ushort* hx1 = (ushort*)(ws + 2269184);     // 262144
    uint*  ctr  = (uint*)(ws + 2531328);       // 256

    k_pack_w<<<(NB * GC * CH + 255) / 256, 256, 0, stream>>>(Wdg0, Whg0, W0P);
    k_pack_w<<<(NB * GC * CH + 255) / 256, 256, 0, stream>>>(Wdg1, Whg1, W1P);
    k_pack_wp<<<4, 256, 0, stream>>>(Wp0, WPQ);
    k_transpose<<<(H_DIM * H_DIM + 255) / 256, 256, 0, stream>>>(Wh1, Wh1T, H_DIM, H_DIM);
    k_transpose<<<(H_DIM * FL_DIM + 255) / 256, 256, 0, stream>>>(Wf1, Wf1T, H_DIM, FL_DIM);
    k_igate<<<B_DIM, H_DIM, 0, stream>>>(stat, Wsh0, bsh0, ig0);
    k_igate<<<B_DIM, H_DIM, 0, stream>>>(stat, Wsh1, bsh1, ig1);
    hipMemsetAsync(ctr, 0, 2 * NCL * sizeof(uint), stream);
    k_main<<<NB * NCL, THR, 0, stream>>>(x, W0P, W1P, WPQ, bdg0, bdg1, bp0,
                                         ig0, ig1, hx0, hx1, hfin, ctr);
    k_heads<<<B_DIM / 2, 256, 0, stream>>>(hfin, fut, Wh1T, bh1, Wh2, bh2,
                                           Wf1T, bf1, Wf2, bf2, (float*)d_out);
}

// Round 8
// 17702.043 us; speedup vs baseline: 2.0107x; 2.0107x over previous
//
#include <hip/hip_runtime.h>
#include <math.h>

#define B_DIM 256
#define T_DIM 365
#define I_DIM 32
#define H_DIM 256
#define S_DIM 27
#define L_DIM 7
#define FL_DIM 56
#define G3 768
#define NC_A0 36   // uint4 chunks for [x|h0] (K=288 -> 36 chunks of 8 f16)
#define NC_A1 32   // uint4 chunks for h1 (K=256)
#define NC_A  68
#define NC_B  4    // uint4 chunks for inp1 (K=32)
#define PD    4    // pipeline depth (named regs p0..p3)

typedef __attribute__((ext_vector_type(2))) _Float16 half2v;

__device__ __forceinline__ float fast_rcp(float x) { return __builtin_amdgcn_rcpf(x); }
__device__ __forceinline__ float sigm(float x) { return fast_rcp(1.0f + __expf(-x)); }
__device__ __forceinline__ float tanh_fast(float x) { return 1.0f - 2.0f * fast_rcp(1.0f + __expf(2.0f * x)); }

__device__ __forceinline__ float dot2(uint w, uint s, float acc) {
#if __has_builtin(__builtin_amdgcn_fdot2)
    return __builtin_amdgcn_fdot2(__builtin_bit_cast(half2v, w), __builtin_bit_cast(half2v, s), acc, false);
#else
    half2v a = __builtin_bit_cast(half2v, w), b = __builtin_bit_cast(half2v, s);
    return acc + (float)a.x * (float)b.x + (float)a.y * (float)b.y;
#endif
}
__device__ __forceinline__ ushort f16bits(float v) {
    _Float16 h = (_Float16)v;
    return __builtin_bit_cast(ushort, h);
}

// WA layout: uint idx = ((c*G3)+g)*4 + j ; chunk c<36: k2=4c+j over [x|h0] layer0 weights,
// c>=36: k2=4(c-36)+j over Whg1. Value = f16x2(W[g][2k2], W[g][2k2+1]).
__global__ void k_pack_A(const float* __restrict__ Wdg0, const float* __restrict__ Whg0,
                         const float* __restrict__ Whg1, uint* __restrict__ WA) {
    int idx = blockIdx.x * 256 + threadIdx.x;
    if (idx >= NC_A * G3 * 4) return;
    int j = idx & 3;
    int g = (idx >> 2) % G3;
    int c = idx / (4 * G3);
    float w0, w1;
    if (c < NC_A0) {
        int k2 = 4 * c + j;
        int k0 = 2 * k2, k1 = k0 + 1;
        w0 = (k0 < I_DIM) ? Wdg0[g * I_DIM + k0] : Whg0[g * H_DIM + (k0 - I_DIM)];
        w1 = (k1 < I_DIM) ? Wdg0[g * I_DIM + k1] : Whg0[g * H_DIM + (k1 - I_DIM)];
    } else {
        int k2 = 4 * (c - NC_A0) + j;
        int k0 = 2 * k2, k1 = k0 + 1;
        w0 = Whg1[g * H_DIM + k0];
        w1 = Whg1[g * H_DIM + k1];
    }
    half2v p; p.x = (_Float16)w0; p.y = (_Float16)w1;
    WA[idx] = __builtin_bit_cast(uint, p);
}

__global__ void k_pack_B(const float* __restrict__ Wdg1, uint* __restrict__ WB) {
    int idx = blockIdx.x * 256 + threadIdx.x;
    if (idx >= NC_B * G3 * 4) return;
    int j = idx & 3;
    int g = (idx >> 2) % G3;
    int c = idx / (4 * G3);
    int k2 = 4 * c + j;
    int k0 = 2 * k2, k1 = k0 + 1;
    half2v p; p.x = (_Float16)Wdg1[g * I_DIM + k0]; p.y = (_Float16)Wdg1[g * I_DIM + k1];
    WB[idx] = __builtin_bit_cast(uint, p);
}

__global__ void k_transpose(const float* __restrict__ in, float* __restrict__ out, int M, int N) {
    int idx = blockIdx.x * 256 + threadIdx.x;
    if (idx >= M * N) return;
    int n = idx / M, m = idx % M;
    out[idx] = in[m * N + n];
}

__global__ void k_igate(const float* __restrict__ st, const float* __restrict__ Wsh,
                        const float* __restrict__ bsh, float* __restrict__ ig) {
    __shared__ float s[S_DIM];
    int b = blockIdx.x, h = threadIdx.x;
    if (h < S_DIM) s[h] = st[b * S_DIM + h];
    __syncthreads();
    float a = bsh[h];
    for (int k = 0; k < S_DIM; ++k) a += s[k] * Wsh[h * S_DIM + k];
    ig[b * H_DIM + h] = sigm(a);
}

// Persistent kernel: block = 2 batch rows, 768 threads (12 waves).
// Phase A streams weights through a 4-deep NAMED-REGISTER pipeline (p0..p3) —
// macro-expanded straight-line code, no arrays, structurally spill-proof.
__global__ __launch_bounds__(768, 3) void k_main(
    const float* __restrict__ x, const float* __restrict__ future,
    const uint* __restrict__ WA, const uint* __restrict__ WB,
    const float* __restrict__ bdg0, const float* __restrict__ bdg1,
    const float* __restrict__ ig0, const float* __restrict__ ig1,
    const float* __restrict__ WpT, const float* __restrict__ bp0,
    const float* __restrict__ Wh1T, const float* __restrict__ bh1,
    const float* __restrict__ Wh2, const float* __restrict__ bh2,
    const float* __restrict__ Wf1T, const float* __restrict__ bf1,
    const float* __restrict__ Wf2, const float* __restrict__ bf2,
    float* __restrict__ out) {
    __shared__ float wp_l[H_DIM * I_DIM];        // proj weights staged once (32 KB)
    __shared__ uint4 xr0A[NC_A0], xr1A[NC_A0];   // [x_t | h0] f16x2 per row
    __shared__ uint4 hr0[NC_A1], hr1[NC_A1];     // h1 f16x2 per row
    __shared__ uint4 xq1x0[NC_B], xq1x1[NC_B];   // inp1 f16x2 per row
    __shared__ float pre0[3][2][H_DIM];
    __shared__ float pre1[3][2][H_DIM];
    __shared__ float hbuf[2][H_DIM];             // h0 fp32
    __shared__ float hbuf1[2][H_DIM];            // h1 fp32
    __shared__ float pbuf[4][64];
    __shared__ float futs[2][FL_DIM];

    const int t = threadIdx.x;
    const int r0 = blockIdx.x * 2;

    uint4 u4z = make_uint4(0u, 0u, 0u, 0u);
    if (t < NC_A0) { xr0A[t] = u4z; xr1A[t] = u4z; }
    if (t < NC_A1) { hr0[t] = u4z; hr1[t] = u4z; }
    for (int j = t; j < H_DIM * I_DIM; j += 768) wp_l[j] = WpT[j];
    __syncthreads();
    if (t < 64) {                                  // stage x_0
        int row = t >> 5, i = t & 31;
        float v = x[(r0 + row) * (T_DIM * I_DIM) + i];
        if (row == 0) ((ushort*)xr0A)[i] = f16bits(v);
        else          ((ushort*)xr1A)[i] = f16bits(v);
    }
    const float bia0 = bdg0[t], bia1 = bdg1[t];
    float ig00 = 0.f, ig01 = 0.f, ig10 = 0.f, ig11 = 0.f;
    float c00 = 0.f, c01 = 0.f, c10 = 0.f, c11 = 0.f;
    if (t < H_DIM) {
        ig00 = ig0[(r0 + 0) * H_DIM + t]; ig01 = ig0[(r0 + 1) * H_DIM + t];
        ig10 = ig1[(r0 + 0) * H_DIM + t]; ig11 = ig1[(r0 + 1) * H_DIM + t];
    }
    const int col = t & 255, which = t >> 8;
    const uint4* wa = (const uint4*)WA + t;
    // phase-B weights are step-invariant: load once, hold in registers (16 VGPRs)
    const uint4* wb = (const uint4*)WB + t;
    const uint4 wbv0 = wb[0 * G3], wbv1 = wb[1 * G3], wbv2 = wb[2 * G3], wbv3 = wb[3 * G3];
    __syncthreads();

// NOTE: macro params deliberately avoid tokens x/y/z/w/s (vector member names).
#define DOT4(W_, S_, A_) { A_ = dot2(W_.x, S_.x, A_); A_ = dot2(W_.y, S_.y, A_); \
                           A_ = dot2(W_.z, S_.z, A_); A_ = dot2(W_.w, S_.w, A_); }
#define CHUNK(C_, WV_) { \
    if ((C_) < NC_A0) { uint4 q0_ = xr0A[(C_)], q1_ = xr1A[(C_)]; \
        DOT4(WV_, q0_, a0); DOT4(WV_, q1_, a1); \
    } else { uint4 q0_ = hr0[(C_)-NC_A0], q1_ = hr1[(C_)-NC_A0]; \
        DOT4(WV_, q0_, b0); DOT4(WV_, q1_, b1); } }
// consume chunk C_ from named reg P_, then refill P_ with chunk C_+PD (compile-time guard)
#define STEP(C_, P_) { \
    uint4 nxt_; \
    if ((C_) + PD < NC_A) nxt_ = wa[((C_) + PD) * G3]; else nxt_ = P_; \
    CHUNK(C_, P_); \
    P_ = nxt_; }
#define S4X(CB_) STEP((CB_) + 0, p0) STEP((CB_) + 1, p1) STEP((CB_) + 2, p2) STEP((CB_) + 3, p3)

    for (int ts = 0; ts < T_DIM; ++ts) {
        // ---- Phase A: layer0 full K + layer1 recurrent K, 4-deep named-reg pipeline
        float a0 = bia0, a1 = bia0;
        float b0 = bia1, b1 = bia1;
        {
            uint4 p0 = wa[0 * G3], p1 = wa[1 * G3], p2 = wa[2 * G3], p3 = wa[3 * G3];
            S4X(0)  S4X(4)  S4X(8)  S4X(12) S4X(16) S4X(20) S4X(24) S4X(28)
            S4X(32) S4X(36) S4X(40) S4X(44) S4X(48) S4X(52) S4X(56) S4X(60)
            S4X(64)
        }
        pre0[which][0][col] = a0; pre0[which][1][col] = a1;
        __syncthreads();                               // S1
        // ---- update 0 (t<256) + stage x_{t+1}
        if (t < H_DIM) {
            float f0 = sigm(pre0[0][0][t]), f1 = sigm(pre0[0][1][t]);
            float o0 = sigm(pre0[1][0][t]), o1 = sigm(pre0[1][1][t]);
            float g0 = tanh_fast(pre0[2][0][t]), g1 = tanh_fast(pre0[2][1][t]);
            c00 = f0 * c00 + ig00 * g0; c01 = f1 * c01 + ig01 * g1;
            float h00 = o0 * tanh_fast(c00), h01 = o1 * tanh_fast(c01);
            hbuf[0][t] = h00; hbuf[1][t] = h01;
            ((ushort*)xr0A)[I_DIM + t] = f16bits(h00);
            ((ushort*)xr1A)[I_DIM + t] = f16bits(h01);
        } else if (t >= 512 && t < 576 && ts + 1 < T_DIM) {
            int tt = t - 512, row = tt >> 5, i = tt & 31;
            float v = x[(r0 + row) * (T_DIM * I_DIM) + (ts + 1) * I_DIM + i];
            if (row == 0) ((ushort*)xr0A)[i] = f16bits(v);
            else          ((ushort*)xr1A)[i] = f16bits(v);
        }
        __syncthreads();                               // S2
        // ---- projection partials (threads 256..511), weights from LDS
        if (t >= 256 && t < 512) {
            int t2 = t - 256, i = t2 & 63, slice = t2 >> 6;
            int row = i >> 5, cp = i & 31;
            const float* hb = hbuf[row];
            const float* wp = wp_l + cp;
            float acc = 0.f;
            int h0i = slice * 64;
#pragma unroll 8
            for (int h = h0i; h < h0i + 64; ++h) acc += hb[h] * wp[h * I_DIM];
            pbuf[slice][i] = acc;
        }
        __syncthreads();                               // S3
        if (t < 32) {
            int row = t >> 4, jp = t & 15;
            int i0 = row * 32 + 2 * jp, i1 = i0 + 1;
            float v0 = pbuf[0][i0] + pbuf[1][i0] + pbuf[2][i0] + pbuf[3][i0] + bp0[2 * jp];
            float v1 = pbuf[0][i1] + pbuf[1][i1] + pbuf[2][i1] + pbuf[3][i1] + bp0[2 * jp + 1];
            half2v p; p.x = (_Float16)v0; p.y = (_Float16)v1;
            uint pw = __builtin_bit_cast(uint, p);
            if (row == 0) ((uint*)xq1x0)[jp] = pw;
            else          ((uint*)xq1x1)[jp] = pw;
        }
        __syncthreads();                               // S4
        // ---- Phase B: tiny inp1 gemm (K=32) from register-resident weights
        {
            uint4 s00 = xq1x0[0], s10 = xq1x1[0];
            DOT4(wbv0, s00, b0); DOT4(wbv0, s10, b1);
            uint4 s01 = xq1x0[1], s11 = xq1x1[1];
            DOT4(wbv1, s01, b0); DOT4(wbv1, s11, b1);
            uint4 s02 = xq1x0[2], s12 = xq1x1[2];
            DOT4(wbv2, s02, b0); DOT4(wbv2, s12, b1);
            uint4 s03 = xq1x0[3], s13 = xq1x1[3];
            DOT4(wbv3, s03, b0); DOT4(wbv3, s13, b1);
        }
        pre1[which][0][col] = b0; pre1[which][1][col] = b1;
        __syncthreads();                               // S5
        // ---- update 1 (t<256)
        if (t < H_DIM) {
            float f0 = sigm(pre1[0][0][t]), f1 = sigm(pre1[0][1][t]);
            float o0 = sigm(pre1[1][0][t]), o1 = sigm(pre1[1][1][t]);
            float g0 = tanh_fast(pre1[2][0][t]), g1 = tanh_fast(pre1[2][1][t]);
            c10 = f0 * c10 + ig10 * g0; c11 = f1 * c11 + ig11 * g1;
            float h10 = o0 * tanh_fast(c10), h11 = o1 * tanh_fast(c11);
            hbuf1[0][t] = h10; hbuf1[1][t] = h11;
            ((ushort*)hr0)[t] = f16bits(h10);
            ((ushort*)hr1)[t] = f16bits(h11);
        }
        __syncthreads();                               // S6 (h1 visible to next Phase A)
    }

    // ---- heads
    if (t < 2 * FL_DIM) { int row = t / FL_DIM, k = t % FL_DIM; futs[row][k] = future[(r0 + row) * FL_DIM + k]; }
    if (t < H_DIM) {
        float a0 = bh1[t], a1 = bh1[t];
        for (int h = 0; h < H_DIM; ++h) {
            float w = Wh1T[h * H_DIM + t];
            a0 += w * hbuf1[0][h]; a1 += w * hbuf1[1][h];
        }
        pre0[0][0][t] = fmaxf(a0, 0.f); pre0[0][1][t] = fmaxf(a1, 0.f);
    }
    __syncthreads();
    if (t < H_DIM) {
        float b0 = bf1[t], b1 = bf1[t];
        for (int k = 0; k < FL_DIM; ++k) {
            float w = Wf1T[k * H_DIM + t];
            b0 += w * futs[0][k]; b1 += w * futs[1][k];
        }
        pre0[1][0][t] = fmaxf(b0, 0.f); pre0[1][1][t] = fmaxf(b1, 0.f);
    }
    __syncthreads();
    if (t < 2 * L_DIM) {
        int row = t / L_DIM, l = t % L_DIM;
        float acc = bh2[l] + bf2[l];
        for (int j = 0; j < H_DIM; ++j)
            acc += pre0[0][row][j] * Wh2[l * H_DIM + j] + pre0[1][row][j] * Wf2[l * H_DIM + j];
        out[(r0 + row) * L_DIM + l] = acc;
    }
#undef S4X
#undef STEP
#undef CHUNK
#undef DOT4
}

extern "C" void kernel_launch(void* const* d_in, const int* in_sizes, int n_in,
                              void* d_out, int out_size, void* d_ws, size_t ws_size,
                              hipStream_t stream) {
    const float* x    = (const float*)d_in[0];
    const float* stat = (const float*)d_in[1];
    const float* fut  = (const float*)d_in[2];
    const float* Wsh0 = (const float*)d_in[3];
    const float* bsh0 = (const float*)d_in[4];
    const float* Wdg0 = (const float*)d_in[5];
    const float* bdg0 = (const float*)d_in[6];
    const float* Whg0 = (const float*)d_in[7];
    const float* Wsh1 = (const float*)d_in[8];
    const float* bsh1 = (const float*)d_in[9];
    const float* Wdg1 = (const float*)d_in[10];
    const float* bdg1 = (const float*)d_in[11];
    const float* Whg1 = (const float*)d_in[12];
    const float* Wp0  = (const float*)d_in[13];
    const float* bp0  = (const float*)d_in[14];
    const float* Wh1  = (const float*)d_in[15];
    const float* bh1  = (const float*)d_in[16];
    const float* Wh2  = (const float*)d_in[17];
    const float* bh2  = (const float*)d_in[18];
    const float* Wf1  = (const float*)d_in[19];
    const float* bf1  = (const float*)d_in[20];
    const float* Wf2  = (const float*)d_in[21];
    const float* bf2  = (const float*)d_in[22];

    float* ws   = (float*)d_ws;
    uint*  WA   = (uint*)ws;                      // 68*768*4 uints
    uint*  WB   = WA + NC_A * G3 * 4;             // 4*768*4
    float* WpT  = (float*)(WB + NC_B * G3 * 4);   // 256*32
    float* Wh1T = WpT + H_DIM * I_DIM;            // 256*256
    float* Wf1T = Wh1T + H_DIM * H_DIM;           // 56*256
    float* ig0  = Wf1T + FL_DIM * H_DIM;          // 256*256
    float* ig1  = ig0 + B_DIM * H_DIM;            // 256*256

    k_pack_A<<<(NC_A * G3 * 4 + 255) / 256, 256, 0, stream>>>(Wdg0, Whg0, Whg1, WA);
    k_pack_B<<<(NC_B * G3 * 4 + 255) / 256, 256, 0, stream>>>(Wdg1, WB);
    k_transpose<<<(I_DIM * H_DIM + 255) / 256, 256, 0, stream>>>(Wp0, WpT, I_DIM, H_DIM);
    k_transpose<<<(H_DIM * H_DIM + 255) / 256, 256, 0, stream>>>(Wh1, Wh1T, H_DIM, H_DIM);
    k_transpose<<<(H_DIM * FL_DIM + 255) / 256, 256, 0, stream>>>(Wf1, Wf1T, H_DIM, FL_DIM);
    k_igate<<<B_DIM, H_DIM, 0, stream>>>(stat, Wsh0, bsh0, ig0);
    k_igate<<<B_DIM, H_DIM, 0, stream>>>(stat, Wsh1, bsh1, ig1);
    k_main<<<B_DIM / 2, 768, 0, stream>>>(x, fut, WA, WB, bdg0, bdg1, ig0, ig1,
                                          WpT, bp0, Wh1T, bh1, Wh2, bh2, Wf1T, bf1, Wf2, bf2,
                                          (float*)d_out);
}